// Round 6
// baseline (2234.192 us; speedup 1.0000x reference)
//
#include <hip/hip_runtime.h>
#include <hip/hip_bf16.h>
#include <cstddef>

#define T_LEN 2048
#define H2 256
#define G4 1024   // 4*H2
#define NLBL 32
#define CLS_TAG 0
#define SEP_TAG 31

// ---------------- helpers ----------------

#if defined(__has_builtin)
#if __has_builtin(__builtin_amdgcn_sdot4)
#define HAS_SDOT4 1
#endif
#if __has_builtin(__builtin_amdgcn_rcpf)
#define HAS_RCPF 1
#endif
#endif

// int8 dot4 via inline asm, "v" constraints: copy-per-use from AGPR would be
// maximally expensive inside the hot loop, pushing the RA toward ArchVGPRs.
__device__ __forceinline__ void sdot(int& acc, int a, int b) {
#if defined(__gfx950__) || defined(__gfx942__) || defined(__gfx90a__)
    asm("v_dot4_i32_i8 %0, %1, %2, %0" : "+v"(acc) : "v"(a), "v"(b));
#elif defined(HAS_SDOT4)
    acc = __builtin_amdgcn_sdot4(a, b, acc, false);
#else
    acc += (int)((signed char)(a & 0xff))         * (int)((signed char)(b & 0xff));
    acc += (int)((signed char)((a >> 8) & 0xff))  * (int)((signed char)((b >> 8) & 0xff));
    acc += (int)((signed char)((a >> 16) & 0xff)) * (int)((signed char)((b >> 16) & 0xff));
    acc += (int)((signed char)(a >> 24))          * (int)((signed char)(b >> 24));
#endif
}

__device__ __forceinline__ float rcpf(float x) {
#ifdef HAS_RCPF
    return __builtin_amdgcn_rcpf(x);
#else
    return 1.0f / x;
#endif
}

__device__ __forceinline__ float sigf(float x) {
    return rcpf(1.0f + __expf(-x));
}

__device__ __forceinline__ float tanhf_(float x) {
    x = fminf(fmaxf(x, -15.0f), 15.0f);
    float e = __expf(2.0f * x);
    return (e - 1.0f) * rcpf(e + 1.0f);
}

#define REP16(M) M(0) M(1) M(2) M(3) M(4) M(5) M(6) M(7) \
                 M(8) M(9) M(10) M(11) M(12) M(13) M(14) M(15)

// ---------------- kernels ----------------

// 1. gather embeddings
__global__ __launch_bounds__(256) void gather_k(const int* __restrict__ ids,
                                                const float* __restrict__ emb,
                                                float* __restrict__ xbuf) {
    int t = blockIdx.x;
    int row = ids[t];
    xbuf[(size_t)t * 256 + threadIdx.x] = emb[(size_t)row * 256 + threadIdx.x];
}

// 2. quantize w_hh (per-row symmetric int8) into PERMUTED row order:
//    original gate-row n (i/f/g/o blocks of 256) -> prow = (n&255)*4 + (n>>8)
__global__ __launch_bounds__(256) void quant_w_k(const float* __restrict__ w_hh_f,
                                                 const float* __restrict__ w_hh_b,
                                                 signed char* __restrict__ wq,
                                                 float* __restrict__ srowP) {
    int wave = threadIdx.x >> 6, lane = threadIdx.x & 63;
    int rg = blockIdx.x * 4 + wave;              // 0..2047
    int dir = rg >> 10, m = rg & 1023;
    int prow = (m & 255) * 4 + (m >> 8);
    const float* src = (dir ? w_hh_b : w_hh_f) + (size_t)m * H2;
    float4 w4 = ((const float4*)src)[lane];
    float mx = fmaxf(fmaxf(fabsf(w4.x), fabsf(w4.y)), fmaxf(fabsf(w4.z), fabsf(w4.w)));
    #pragma unroll
    for (int off = 32; off; off >>= 1) mx = fmaxf(mx, __shfl_xor(mx, off, 64));
    float s = (mx > 0.0f) ? mx * (1.0f / 127.0f) : 1.0f;
    float inv = rcpf(s);
    int q0 = __float2int_rn(w4.x * inv);
    int q1 = __float2int_rn(w4.y * inv);
    int q2 = __float2int_rn(w4.z * inv);
    int q3 = __float2int_rn(w4.w * inv);
    int packed = (q0 & 255) | ((q1 & 255) << 8) | ((q2 & 255) << 16) | ((q3 & 255) << 24);
    ((int*)wq)[((size_t)(dir * G4 + prow)) * 64 + lane] = packed;
    if (lane == 0) srowP[dir * G4 + prow] = s;
}

// 3. quantize h0 (per-direction scale), bytes unit-ascending.
__global__ __launch_bounds__(64) void quant_h0_k(const float* __restrict__ h0,
                                                 int* __restrict__ hq0,
                                                 float* __restrict__ sh0) {
    int dir = blockIdx.x, lane = threadIdx.x;
    float4 h4 = ((const float4*)(h0 + (size_t)dir * H2))[lane];
    float m = fmaxf(fmaxf(fabsf(h4.x), fabsf(h4.y)), fmaxf(fabsf(h4.z), fabsf(h4.w)));
    #pragma unroll
    for (int off = 32; off; off >>= 1) m = fmaxf(m, __shfl_xor(m, off, 64));
    float s = (m > 0.0f) ? m * (1.0f / 127.0f) : 1.0f;
    float inv = rcpf(s);
    int q0 = __float2int_rn(h4.x * inv);
    int q1 = __float2int_rn(h4.y * inv);
    int q2 = __float2int_rn(h4.z * inv);
    int q3 = __float2int_rn(h4.w * inv);
    hq0[dir * 64 + lane] = (q0 & 255) | ((q1 & 255) << 8) | ((q2 & 255) << 16) | ((q3 & 255) << 24);
    if (lane == 0) sh0[dir] = s;
}

// 4. xproj GEMM -> PERMUTED output: xprojP[dir][t][u*4+g]
__global__ __launch_bounds__(256) void gemm_xproj_k(const float* __restrict__ xbuf,
                                                    const float* __restrict__ w_ih_f,
                                                    const float* __restrict__ w_ih_b,
                                                    const float* __restrict__ b_f,
                                                    const float* __restrict__ b_b,
                                                    float* __restrict__ xprojP) {
    __shared__ float As[64][33];
    __shared__ float Bs[64][33];
    int tid = threadIdx.x;
    int t0 = blockIdx.x * 64;
    int n0 = blockIdx.y * 64;
    int tx = tid & 15, ty = tid >> 4;
    float acc[4][4] = {};
    for (int k0 = 0; k0 < 256; k0 += 32) {
        #pragma unroll
        for (int i = 0; i < 8; ++i) {
            int idx = tid + i * 256;
            int r = idx >> 5, kk = idx & 31;
            As[r][kk] = xbuf[(size_t)(t0 + r) * 256 + k0 + kk];
            int nn = n0 + r;
            const float* wsrc = (nn < 1024) ? (w_ih_f + (size_t)nn * 256)
                                            : (w_ih_b + (size_t)(nn - 1024) * 256);
            Bs[r][kk] = wsrc[k0 + kk];
        }
        __syncthreads();
        #pragma unroll
        for (int kk = 0; kk < 32; ++kk) {
            float a[4], b[4];
            #pragma unroll
            for (int i = 0; i < 4; ++i) a[i] = As[ty * 4 + i][kk];
            #pragma unroll
            for (int j = 0; j < 4; ++j) b[j] = Bs[tx * 4 + j][kk];
            #pragma unroll
            for (int i = 0; i < 4; ++i)
                #pragma unroll
                for (int j = 0; j < 4; ++j) acc[i][j] += a[i] * b[j];
        }
        __syncthreads();
    }
    #pragma unroll
    for (int j = 0; j < 4; ++j) {
        int nn = n0 + tx * 4 + j;
        int dir = nn >> 10, nl = nn & 1023;
        float bias = dir ? b_b[nl] : b_f[nl];
        int pidx = (nl & 255) * 4 + (nl >> 8);
        #pragma unroll
        for (int i = 0; i < 4; ++i) {
            int t = t0 + ty * 4 + i;
            xprojP[((size_t)dir * T_LEN + t) * G4 + pidx] = acc[i][j] + bias;
        }
    }
}

// 5. LSTM recurrence v6: pair-thread structure of v5, but the 128 weight
//    dwords are 128 INDIVIDUAL named scalars (no int4 tuples) loaded via
//    volatile dword loads -> independent live ranges the RA can place in
//    ArchVGPRs (tuple live ranges kept demoting to AGPR, v3/v5: VGPR=84/80).
__global__ __launch_bounds__(512, 2) void lstm_rec_k(const signed char* __restrict__ wq,
                                                     const float* __restrict__ srowP,
                                                     const float* __restrict__ xprojP,
                                                     const int* __restrict__ hq0,
                                                     const float* __restrict__ sh0v,
                                                     const float* __restrict__ c0,
                                                     float* __restrict__ hs) {
    const int dir = blockIdx.x;
    const int x = threadIdx.x;            // 0..511
    const int u = x >> 1;                 // unit
    const bool lo = (x & 1) == 0;         // even: gates i,f ; odd: g,o
    __shared__ int hqs[2][64];            // packed int8 h, ping-pong

    // 128 weight dwords as discrete scalars. volatile defeats load-merging
    // into b128 tuples (one-time cost; the loop below runs 2048 iters).
    volatile const int* wpv = (const int*)wq + ((size_t)(dir * G4 + 2 * x)) * 64;
#define DECLW(g) \
    int wa_##g##_0 = wpv[4*(g)+0],    wa_##g##_1 = wpv[4*(g)+1], \
        wa_##g##_2 = wpv[4*(g)+2],    wa_##g##_3 = wpv[4*(g)+3], \
        wb_##g##_0 = wpv[64+4*(g)+0], wb_##g##_1 = wpv[64+4*(g)+1], \
        wb_##g##_2 = wpv[64+4*(g)+2], wb_##g##_3 = wpv[64+4*(g)+3];
    REP16(DECLW)
#undef DECLW

    float2 sr = ((const float2*)(srowP + dir * G4))[x];
    float sh = sh0v[dir];
    float c = c0[dir * H2 + u];           // replicated per pair
    const float2* xp2 = (const float2*)(xprojP + (size_t)dir * T_LEN * G4);
    if (x < 64) hqs[0][x] = hq0[dir * 64 + x];

    int t = dir ? (T_LEN - 1) : 0;
    const int stp = dir ? -1 : 1;
    float2 zx = xp2[(size_t)t * 512 + x];
    __syncthreads();

    for (int s = 0; s < T_LEN; ++s) {
        const int buf = s & 1;
        int tn = (s == T_LEN - 1) ? t : t + stp;
        float2 zxn = xp2[(size_t)tn * 512 + x];          // prefetch next step

        int a0 = 0, a1 = 0;
        const int4* hb = (const int4*)(&hqs[buf][0]);
#define DOTG(g) { int4 hv = hb[g]; \
        sdot(a0, wa_##g##_0, hv.x); sdot(a1, wb_##g##_0, hv.x); \
        sdot(a0, wa_##g##_1, hv.y); sdot(a1, wb_##g##_1, hv.y); \
        sdot(a0, wa_##g##_2, hv.z); sdot(a1, wb_##g##_2, hv.z); \
        sdot(a0, wa_##g##_3, hv.w); sdot(a1, wb_##g##_3, hv.w); }
        REP16(DOTG)
#undef DOTG

        float z0 = zx.x + sr.x * sh * (float)a0;
        float z1 = zx.y + sr.y * sh * (float)a1;
        float zp0 = __shfl_xor(z0, 1, 64);                // partner's gates
        float zp1 = __shfl_xor(z1, 1, 64);
        float zi = lo ? z0 : zp0;
        float zf = lo ? z1 : zp1;
        float zg = lo ? zp0 : z0;
        float zo = lo ? zp1 : z1;
        float ig = sigf(zi), fg = sigf(zf), gg = tanhf_(zg), og = sigf(zo);
        c = fg * c + ig * gg;
        float h = og * tanhf_(c);
        int qv = __float2int_rn(fminf(fmaxf(h * 127.0f, -127.0f), 127.0f));
        if (lo) {
            hs[(size_t)t * 512 + dir * H2 + u] = h;
            ((signed char*)hqs[1 - buf])[u] = (signed char)qv;
        }
        sh = 1.0f / 127.0f;
        zx = zxn;
        t = tn;
        __syncthreads();                                  // publish hqs[1-buf]
    }
}

// 6. logits
__global__ __launch_bounds__(128) void logits_k(const float* __restrict__ hs,
                                                const float* __restrict__ w_lin,
                                                const float* __restrict__ b_lin,
                                                float* __restrict__ logits) {
    __shared__ float wldT[512][17];
    __shared__ float hld[8][512];
    int tid = threadIdx.x;
    int t0 = blockIdx.x * 8;
    int n0 = blockIdx.y * 16;
    for (int i = tid; i < 16 * 512; i += 128) {
        int j = i >> 9, k = i & 511;
        wldT[k][j] = w_lin[(size_t)(n0 + j) * 512 + k];
    }
    for (int i = tid; i < 8 * 512; i += 128) {
        int tq = i >> 9, k = i & 511;
        hld[tq][k] = hs[(size_t)(t0 + tq) * 512 + k];
    }
    __syncthreads();
    int j = tid & 15, tq = tid >> 4;
    float acc = b_lin[n0 + j];
    #pragma unroll 8
    for (int k = 0; k < 512; ++k) acc += hld[tq][k] * wldT[k][j];
    logits[(size_t)(t0 + tq) * NLBL + n0 + j] = acc;
}

// 7. gold path score
__global__ __launch_bounds__(256) void gold_k(const float* __restrict__ trans,
                                              const int* __restrict__ target,
                                              const float* __restrict__ logits,
                                              float* __restrict__ gold) {
    __shared__ float red[256];
    int tid = threadIdx.x;
    float s = 0.0f;
    for (int t = tid; t < T_LEN; t += 256) {
        int cur = target[t];
        int prev = (t == 0) ? CLS_TAG : target[t - 1];
        s += trans[cur * NLBL + prev] + logits[(size_t)t * NLBL + cur];
    }
    if (tid == 0) s += trans[SEP_TAG * NLBL + target[T_LEN - 1]];
    red[tid] = s;
    __syncthreads();
    for (int st = 128; st; st >>= 1) {
        if (tid < st) red[tid] += red[tid + st];
        __syncthreads();
    }
    if (tid == 0) gold[0] = red[0];
}

// 8a. CRF tree level 0
__global__ __launch_bounds__(1024) void crf_chain0_k(const float* __restrict__ logits,
                                                     const float* __restrict__ trans,
                                                     float* __restrict__ mats) {
    const int tid = threadIdx.x;
    const int n = tid >> 5, p = tid & 31;
    __shared__ float Rl[2][NLBL][NLBL + 1];
    __shared__ float tl[NLBL][NLBL + 1];
    const int t0 = blockIdx.x * 8;
    float e[8];
    #pragma unroll
    for (int s = 0; s < 8; ++s) e[s] = logits[(size_t)(t0 + s) * NLBL + n];
    float myt = trans[n * NLBL + p];
    tl[n][p] = myt;
    __syncthreads();
    float tr[NLBL];
    #pragma unroll
    for (int k = 0; k < NLBL; ++k) tr[k] = tl[n][k];
    Rl[0][n][p] = myt + e[0];
    __syncthreads();
    float rn = 0.0f;
    for (int s = 1; s < 8; ++s) {
        const int cur = (s - 1) & 1, nxt = s & 1;
        float v[NLBL];
        #pragma unroll
        for (int k = 0; k < NLBL; ++k) v[k] = tr[k] + Rl[cur][k][p];
        float m = v[0];
        #pragma unroll
        for (int k = 1; k < NLBL; ++k) m = fmaxf(m, v[k]);
        float sum = 0.0f;
        #pragma unroll
        for (int k = 0; k < NLBL; ++k) sum += __expf(v[k] - m);
        rn = e[s] + m + __logf(sum);
        Rl[nxt][n][p] = rn;
        __syncthreads();
    }
    mats[(size_t)blockIdx.x * 1024 + tid] = rn;
}

// 8b. CRF tree level N
__global__ __launch_bounds__(1024) void crf_chainN_k(const float* __restrict__ min_,
                                                     float* __restrict__ mout,
                                                     int chunk) {
    const int tid = threadIdx.x;
    const int n = tid >> 5, p = tid & 31;
    __shared__ float Rl[2][NLBL][NLBL + 1];
    __shared__ float Al[2][NLBL][NLBL + 1];
    const size_t base = (size_t)blockIdx.x * chunk;
    float rn = min_[base * 1024 + tid];
    Rl[0][n][p] = rn;
    float anext = min_[(base + 1) * 1024 + tid];
    __syncthreads();
    for (int s = 1; s < chunk; ++s) {
        const int cur = (s - 1) & 1, nxt = s & 1;
        Al[nxt][n][p] = anext;
        if (s + 1 < chunk) anext = min_[(base + s + 1) * 1024 + tid];
        __syncthreads();
        float v[NLBL];
        #pragma unroll
        for (int k = 0; k < NLBL; ++k) v[k] = Al[nxt][n][k] + Rl[cur][k][p];
        float m = v[0];
        #pragma unroll
        for (int k = 1; k < NLBL; ++k) m = fmaxf(m, v[k]);
        float sum = 0.0f;
        #pragma unroll
        for (int k = 0; k < NLBL; ++k) sum += __expf(v[k] - m);
        rn = m + __logf(sum);
        Rl[nxt][n][p] = rn;
        __syncthreads();
    }
    mout[(size_t)blockIdx.x * 1024 + tid] = rn;
}

// 8c. CRF finish
__global__ __launch_bounds__(1024) void crf_finish_k(const float* __restrict__ min_,
                                                     const float* __restrict__ trans,
                                                     const float* __restrict__ gold,
                                                     float* __restrict__ out,
                                                     int chunk) {
    const int tid = threadIdx.x;
    const int n = tid >> 5, p = tid & 31;
    __shared__ float Rl[2][NLBL][NLBL + 1];
    __shared__ float Al[2][NLBL][NLBL + 1];
    __shared__ float af[NLBL];
    float rn = min_[tid];
    Rl[0][n][p] = rn;
    float anext = min_[1024 + tid];
    __syncthreads();
    for (int s = 1; s < chunk; ++s) {
        const int cur = (s - 1) & 1, nxt = s & 1;
        Al[nxt][n][p] = anext;
        if (s + 1 < chunk) anext = min_[(size_t)(s + 1) * 1024 + tid];
        __syncthreads();
        float v[NLBL];
        #pragma unroll
        for (int k = 0; k < NLBL; ++k) v[k] = Al[nxt][n][k] + Rl[cur][k][p];
        float m = v[0];
        #pragma unroll
        for (int k = 1; k < NLBL; ++k) m = fmaxf(m, v[k]);
        float sum = 0.0f;
        #pragma unroll
        for (int k = 0; k < NLBL; ++k) sum += __expf(v[k] - m);
        rn = m + __logf(sum);
        Rl[nxt][n][p] = rn;
        __syncthreads();
    }
    float val = rn + ((p == CLS_TAG) ? 0.0f : -10000.0f);
    float m = val;
    #pragma unroll
    for (int off = 16; off; off >>= 1) m = fmaxf(m, __shfl_xor(m, off, 32));
    float esum = __expf(val - m);
    #pragma unroll
    for (int off = 16; off; off >>= 1) esum += __shfl_xor(esum, off, 32);
    if (p == 0) af[n] = m + __logf(esum);
    __syncthreads();
    if (tid < NLBL) {
        float f = af[tid] + trans[SEP_TAG * NLBL + tid];
        float mm = f;
        #pragma unroll
        for (int off = 16; off; off >>= 1) mm = fmaxf(mm, __shfl_xor(mm, off, 32));
        float es = __expf(f - mm);
        #pragma unroll
        for (int off = 16; off; off >>= 1) es += __shfl_xor(es, off, 32);
        if (tid == 0) out[0] = mm + __logf(es) - gold[0];
    }
}

// ---------------- launch ----------------

extern "C" void kernel_launch(void* const* d_in, const int* in_sizes, int n_in,
                              void* d_out, int out_size, void* d_ws, size_t ws_size,
                              hipStream_t stream) {
    const int*   ids     = (const int*)d_in[0];
    const int*   target  = (const int*)d_in[2];
    const float* emb     = (const float*)d_in[3];
    const float* w_ih_f  = (const float*)d_in[4];
    const float* w_hh_f  = (const float*)d_in[5];
    const float* b_f     = (const float*)d_in[6];
    const float* w_ih_b  = (const float*)d_in[7];
    const float* w_hh_b  = (const float*)d_in[8];
    const float* b_b     = (const float*)d_in[9];
    const float* w_lin   = (const float*)d_in[10];
    const float* b_lin   = (const float*)d_in[11];
    const float* trans   = (const float*)d_in[12];
    const float* h0      = (const float*)d_in[13];
    const float* c0      = (const float*)d_in[14];
    float* out = (float*)d_out;

    char* ws = (char*)d_ws;
    size_t off = 0;
    float* xbuf   = (float*)(ws + off); off += (size_t)T_LEN * 256 * 4;       // 2 MB
    float* xprojP = (float*)(ws + off); off += (size_t)2 * T_LEN * G4 * 4;    // 16 MB
    float* hs     = (float*)(ws + off); off += (size_t)T_LEN * 512 * 4;       // 4 MB
    float* logits = (float*)(ws + off); off += (size_t)T_LEN * NLBL * 4;      // 256 KB
    float* srowP  = (float*)(ws + off); off += (size_t)2 * G4 * 4;            // 8 KB
    float* sh0v   = (float*)(ws + off); off += 16;
    float* gold   = (float*)(ws + off); off += 16;
    int*   hq0    = (int*)(ws + off);   off += (size_t)2 * 64 * 4;
    signed char* wq = (signed char*)(ws + off); off += (size_t)2 * G4 * H2;   // 512 KB
    float* mats1 = xbuf;                 // alias xbuf (dead after gemm_xproj)
    float* mats2 = xbuf + 256 * 1024;

    gather_k<<<T_LEN, 256, 0, stream>>>(ids, emb, xbuf);
    quant_w_k<<<512, 256, 0, stream>>>(w_hh_f, w_hh_b, wq, srowP);
    quant_h0_k<<<2, 64, 0, stream>>>(h0, hq0, sh0v);
    gemm_xproj_k<<<dim3(32, 32), 256, 0, stream>>>(xbuf, w_ih_f, w_ih_b, b_f, b_b, xprojP);
    lstm_rec_k<<<2, 512, 0, stream>>>(wq, srowP, xprojP, hq0, sh0v, c0, hs);
    logits_k<<<dim3(256, 2), 128, 0, stream>>>(hs, w_lin, b_lin, logits);
    gold_k<<<1, 256, 0, stream>>>(trans, target, logits, gold);
    crf_chain0_k<<<256, 1024, 0, stream>>>(logits, trans, mats1);
    crf_chainN_k<<<16, 1024, 0, stream>>>(mats1, mats2, 16);
    crf_finish_k<<<1, 1024, 0, stream>>>(mats2, trans, gold, out, 16);
}

// Round 7
// 1968.983 us; speedup vs baseline: 1.1347x; 1.1347x over previous
//
#include <hip/hip_runtime.h>
#include <hip/hip_bf16.h>
#include <cstddef>

#define T_LEN 2048
#define H2 256
#define G4 1024   // 4*H2
#define NLBL 32
#define CLS_TAG 0
#define SEP_TAG 31

// ---------------- helpers ----------------

#if defined(__has_builtin)
#if __has_builtin(__builtin_amdgcn_sdot8)
#define HAS_SDOT8 1
#endif
#if __has_builtin(__builtin_amdgcn_rcpf)
#define HAS_RCPF 1
#endif
#endif

// int8x4? no: int4x8 dot: acc += sum_m sext(a.nib[m]) * sext(b.nib[m])
__device__ __forceinline__ void dot8(int& acc, int a, int b) {
#if defined(HAS_SDOT8)
    acc = __builtin_amdgcn_sdot8(a, b, acc, false);
#elif defined(__gfx950__) || defined(__gfx942__) || defined(__gfx90a__)
    asm("v_dot8_i32_i4 %0, %1, %2, %0" : "+v"(acc) : "v"(a), "v"(b));
#else
    #pragma unroll
    for (int m = 0; m < 8; ++m) {
        int av = (a << (28 - 4 * m)) >> 28;
        int bv = (b << (28 - 4 * m)) >> 28;
        acc += av * bv;
    }
#endif
}

__device__ __forceinline__ float rcpf(float x) {
#ifdef HAS_RCPF
    return __builtin_amdgcn_rcpf(x);
#else
    return 1.0f / x;
#endif
}

__device__ __forceinline__ float sigf(float x) {
    return rcpf(1.0f + __expf(-x));
}

__device__ __forceinline__ float tanhf_(float x) {
    x = fminf(fmaxf(x, -15.0f), 15.0f);
    float e = __expf(2.0f * x);
    return (e - 1.0f) * rcpf(e + 1.0f);
}

// ---------------- kernels ----------------

// 1. gather embeddings
__global__ __launch_bounds__(256) void gather_k(const int* __restrict__ ids,
                                                const float* __restrict__ emb,
                                                float* __restrict__ xbuf) {
    int t = blockIdx.x;
    int row = ids[t];
    xbuf[(size_t)t * 256 + threadIdx.x] = emb[(size_t)row * 256 + threadIdx.x];
}

// 2. quantize w_hh to int4 (per-row symmetric, range [-7,7]) into PERMUTED
//    row order prow = (n&255)*4 + (n>>8), packed 8 nibbles/dword with
//    nibble m of dword j = element 8j+m. One wave per row.
__global__ __launch_bounds__(256) void quant_w_k(const float* __restrict__ w_hh_f,
                                                 const float* __restrict__ w_hh_b,
                                                 unsigned int* __restrict__ wq4,
                                                 float* __restrict__ srowP) {
    int wave = threadIdx.x >> 6, lane = threadIdx.x & 63;
    int rg = blockIdx.x * 4 + wave;              // 0..2047
    int dir = rg >> 10, m = rg & 1023;
    int prow = (m & 255) * 4 + (m >> 8);
    const float* src = (dir ? w_hh_b : w_hh_f) + (size_t)m * H2;
    float4 w4 = ((const float4*)src)[lane];      // elements 4*lane .. 4*lane+3
    float mx = fmaxf(fmaxf(fabsf(w4.x), fabsf(w4.y)), fmaxf(fabsf(w4.z), fabsf(w4.w)));
    #pragma unroll
    for (int off = 32; off; off >>= 1) mx = fmaxf(mx, __shfl_xor(mx, off, 64));
    float s = (mx > 0.0f) ? mx * (1.0f / 7.0f) : 1.0f;
    float inv = (mx > 0.0f) ? 7.0f * rcpf(mx) : 0.0f;
    int q0 = __float2int_rn(w4.x * inv);
    int q1 = __float2int_rn(w4.y * inv);
    int q2 = __float2int_rn(w4.z * inv);
    int q3 = __float2int_rn(w4.w * inv);
    unsigned int half = (unsigned)(q0 & 15) | ((unsigned)(q1 & 15) << 4) |
                        ((unsigned)(q2 & 15) << 8) | ((unsigned)(q3 & 15) << 12);
    unsigned int other = (unsigned int)__shfl_xor((int)half, 1, 64);
    if ((lane & 1) == 0)   // even lane: elems 8d..8d+3 (lo 16b), odd: 8d+4..8d+7
        wq4[(size_t)(dir * G4 + prow) * 32 + (lane >> 1)] = half | (other << 16);
    if (lane == 0) srowP[dir * G4 + prow] = s;
}

// 3. quantize h0 to int4 (per-direction scale), packed like above.
__global__ __launch_bounds__(64) void quant_h0_k(const float* __restrict__ h0,
                                                 unsigned int* __restrict__ hq0,
                                                 float* __restrict__ sh0) {
    int dir = blockIdx.x, lane = threadIdx.x;
    float4 h4 = ((const float4*)(h0 + (size_t)dir * H2))[lane];
    float mx = fmaxf(fmaxf(fabsf(h4.x), fabsf(h4.y)), fmaxf(fabsf(h4.z), fabsf(h4.w)));
    #pragma unroll
    for (int off = 32; off; off >>= 1) mx = fmaxf(mx, __shfl_xor(mx, off, 64));
    float s = (mx > 0.0f) ? mx * (1.0f / 7.0f) : 1.0f;
    float inv = (mx > 0.0f) ? 7.0f * rcpf(mx) : 0.0f;
    int q0 = __float2int_rn(h4.x * inv);
    int q1 = __float2int_rn(h4.y * inv);
    int q2 = __float2int_rn(h4.z * inv);
    int q3 = __float2int_rn(h4.w * inv);
    unsigned int half = (unsigned)(q0 & 15) | ((unsigned)(q1 & 15) << 4) |
                        ((unsigned)(q2 & 15) << 8) | ((unsigned)(q3 & 15) << 12);
    unsigned int other = (unsigned int)__shfl_xor((int)half, 1, 64);
    if ((lane & 1) == 0)
        hq0[dir * 32 + (lane >> 1)] = half | (other << 16);
    if (lane == 0) sh0[dir] = s;
}

// 4. xproj GEMM -> PERMUTED output: xprojP[dir][t][u*4+g]
__global__ __launch_bounds__(256) void gemm_xproj_k(const float* __restrict__ xbuf,
                                                    const float* __restrict__ w_ih_f,
                                                    const float* __restrict__ w_ih_b,
                                                    const float* __restrict__ b_f,
                                                    const float* __restrict__ b_b,
                                                    float* __restrict__ xprojP) {
    __shared__ float As[64][33];
    __shared__ float Bs[64][33];
    int tid = threadIdx.x;
    int t0 = blockIdx.x * 64;
    int n0 = blockIdx.y * 64;
    int tx = tid & 15, ty = tid >> 4;
    float acc[4][4] = {};
    for (int k0 = 0; k0 < 256; k0 += 32) {
        #pragma unroll
        for (int i = 0; i < 8; ++i) {
            int idx = tid + i * 256;
            int r = idx >> 5, kk = idx & 31;
            As[r][kk] = xbuf[(size_t)(t0 + r) * 256 + k0 + kk];
            int nn = n0 + r;
            const float* wsrc = (nn < 1024) ? (w_ih_f + (size_t)nn * 256)
                                            : (w_ih_b + (size_t)(nn - 1024) * 256);
            Bs[r][kk] = wsrc[k0 + kk];
        }
        __syncthreads();
        #pragma unroll
        for (int kk = 0; kk < 32; ++kk) {
            float a[4], b[4];
            #pragma unroll
            for (int i = 0; i < 4; ++i) a[i] = As[ty * 4 + i][kk];
            #pragma unroll
            for (int j = 0; j < 4; ++j) b[j] = Bs[tx * 4 + j][kk];
            #pragma unroll
            for (int i = 0; i < 4; ++i)
                #pragma unroll
                for (int j = 0; j < 4; ++j) acc[i][j] += a[i] * b[j];
        }
        __syncthreads();
    }
    #pragma unroll
    for (int j = 0; j < 4; ++j) {
        int nn = n0 + tx * 4 + j;
        int dir = nn >> 10, nl = nn & 1023;
        float bias = dir ? b_b[nl] : b_f[nl];
        int pidx = (nl & 255) * 4 + (nl >> 8);
        #pragma unroll
        for (int i = 0; i < 4; ++i) {
            int t = t0 + ty * 4 + i;
            xprojP[((size_t)dir * T_LEN + t) * G4 + pidx] = acc[i][j] + bias;
        }
    }
}

// 5. LSTM recurrence v7: int4 weights (64 dwords/thread) + v_dot8_i32_i4;
//    h broadcast via ONE ds_read_b32 + readlane (no LDS broadcast storm);
//    pair-thread gates via shfl; nibble h-pack via shfl_xor(2) + byte write;
//    ONE barrier per step.
__global__ __launch_bounds__(512, 2) void lstm_rec_k(const unsigned int* __restrict__ wq4,
                                                     const float* __restrict__ srowP,
                                                     const float* __restrict__ xprojP,
                                                     const unsigned int* __restrict__ hq0,
                                                     const float* __restrict__ sh0v,
                                                     const float* __restrict__ c0,
                                                     float* __restrict__ hs) {
    const int dir = blockIdx.x;
    const int x = threadIdx.x;            // 0..511
    const int lane = x & 63, W = x >> 6;  // wave 0..7
    const int u = x >> 1;                 // unit
    const bool lo = (x & 1) == 0;         // even: gates i,f ; odd: g,o
    __shared__ unsigned int hqs[2][32];   // 256 units x 4-bit, ping-pong

    // weights: permuted rows 2x, 2x+1 -> 2 x 32 int4-dwords
    int w0[32], w1[32];
    {
        const unsigned int* wr = wq4 + (size_t)(dir * G4 + 2 * x) * 32;
        #pragma unroll
        for (int k = 0; k < 32; ++k) w0[k] = (int)wr[k];
        #pragma unroll
        for (int k = 0; k < 32; ++k) w1[k] = (int)wr[32 + k];
    }
    float2 sr = ((const float2*)(srowP + dir * G4))[x];
    float sh = sh0v[dir];
    float c = c0[dir * H2 + u];           // replicated per pair
    const float2* xp2 = (const float2*)(xprojP + (size_t)dir * T_LEN * G4);
    if (x < 32) hqs[0][x] = hq0[dir * 32 + x];

    int t = dir ? (T_LEN - 1) : 0;
    const int stp = dir ? -1 : 1;
    float2 zx = xp2[(size_t)t * 512 + x];
    __syncthreads();

    for (int s = 0; s < T_LEN; ++s) {
        const int buf = s & 1;
        int tn = (s == T_LEN - 1) ? t : t + stp;
        float2 zxn = xp2[(size_t)tn * 512 + x];          // prefetch next step

        // lane j (and j+32) holds h-dword j; k-loop broadcasts via readlane
        int hreg = (int)hqs[buf][lane & 31];
        int a0 = 0, a1 = 0;
        #pragma unroll
        for (int j = 0; j < 32; ++j) {
            int hj = __builtin_amdgcn_readlane(hreg, j);  // uniform (SGPR)
            dot8(a0, w0[j], hj);
            dot8(a1, w1[j], hj);
        }
        float z0 = zx.x + sr.x * sh * (float)a0;
        float z1 = zx.y + sr.y * sh * (float)a1;
        float zp0 = __shfl_xor(z0, 1, 64);                // partner's gates
        float zp1 = __shfl_xor(z1, 1, 64);
        float zi = lo ? z0 : zp0;
        float zf = lo ? z1 : zp1;
        float zg = lo ? zp0 : z0;
        float zo = lo ? zp1 : z1;
        float ig = sigf(zi), fg = sigf(zf), gg = tanhf_(zg), og = sigf(zo);
        c = fg * c + ig * gg;
        float h = og * tanhf_(c);
        // quantize h to int4 in [-7,7], scale 1/7
        int qv = __float2int_rn(fminf(fmaxf(h * 7.0f, -7.0f), 7.0f));
        int nib = qv & 15;
        int pn = __shfl_xor(nib, 2, 64);                  // partner unit's nibble
        if ((lane & 3) == 0) {                            // lane 4m: units 2m,2m+1 of this wave
            unsigned char b = (unsigned char)((nib | (pn << 4)) & 255);
            ((unsigned char*)&hqs[1 - buf][0])[W * 16 + (lane >> 2)] = b;
        }
        if (lo) hs[(size_t)t * 512 + dir * H2 + u] = h;
        sh = 1.0f / 7.0f;                                 // steady-state h scale
        zx = zxn;
        t = tn;
        __syncthreads();                                  // publish hqs[1-buf]
    }
}

// 6. logits
__global__ __launch_bounds__(128) void logits_k(const float* __restrict__ hs,
                                                const float* __restrict__ w_lin,
                                                const float* __restrict__ b_lin,
                                                float* __restrict__ logits) {
    __shared__ float wldT[512][17];
    __shared__ float hld[8][512];
    int tid = threadIdx.x;
    int t0 = blockIdx.x * 8;
    int n0 = blockIdx.y * 16;
    for (int i = tid; i < 16 * 512; i += 128) {
        int j = i >> 9, k = i & 511;
        wldT[k][j] = w_lin[(size_t)(n0 + j) * 512 + k];
    }
    for (int i = tid; i < 8 * 512; i += 128) {
        int tq = i >> 9, k = i & 511;
        hld[tq][k] = hs[(size_t)(t0 + tq) * 512 + k];
    }
    __syncthreads();
    int j = tid & 15, tq = tid >> 4;
    float acc = b_lin[n0 + j];
    #pragma unroll 8
    for (int k = 0; k < 512; ++k) acc += hld[tq][k] * wldT[k][j];
    logits[(size_t)(t0 + tq) * NLBL + n0 + j] = acc;
}

// 7. gold path score
__global__ __launch_bounds__(256) void gold_k(const float* __restrict__ trans,
                                              const int* __restrict__ target,
                                              const float* __restrict__ logits,
                                              float* __restrict__ gold) {
    __shared__ float red[256];
    int tid = threadIdx.x;
    float s = 0.0f;
    for (int t = tid; t < T_LEN; t += 256) {
        int cur = target[t];
        int prev = (t == 0) ? CLS_TAG : target[t - 1];
        s += trans[cur * NLBL + prev] + logits[(size_t)t * NLBL + cur];
    }
    if (tid == 0) s += trans[SEP_TAG * NLBL + target[T_LEN - 1]];
    red[tid] = s;
    __syncthreads();
    for (int st = 128; st; st >>= 1) {
        if (tid < st) red[tid] += red[tid + st];
        __syncthreads();
    }
    if (tid == 0) gold[0] = red[0];
}

// 8a. CRF tree level 0
__global__ __launch_bounds__(1024) void crf_chain0_k(const float* __restrict__ logits,
                                                     const float* __restrict__ trans,
                                                     float* __restrict__ mats) {
    const int tid = threadIdx.x;
    const int n = tid >> 5, p = tid & 31;
    __shared__ float Rl[2][NLBL][NLBL + 1];
    __shared__ float tl[NLBL][NLBL + 1];
    const int t0 = blockIdx.x * 8;
    float e[8];
    #pragma unroll
    for (int s = 0; s < 8; ++s) e[s] = logits[(size_t)(t0 + s) * NLBL + n];
    float myt = trans[n * NLBL + p];
    tl[n][p] = myt;
    __syncthreads();
    float tr[NLBL];
    #pragma unroll
    for (int k = 0; k < NLBL; ++k) tr[k] = tl[n][k];
    Rl[0][n][p] = myt + e[0];
    __syncthreads();
    float rn = 0.0f;
    for (int s = 1; s < 8; ++s) {
        const int cur = (s - 1) & 1, nxt = s & 1;
        float v[NLBL];
        #pragma unroll
        for (int k = 0; k < NLBL; ++k) v[k] = tr[k] + Rl[cur][k][p];
        float m = v[0];
        #pragma unroll
        for (int k = 1; k < NLBL; ++k) m = fmaxf(m, v[k]);
        float sum = 0.0f;
        #pragma unroll
        for (int k = 0; k < NLBL; ++k) sum += __expf(v[k] - m);
        rn = e[s] + m + __logf(sum);
        Rl[nxt][n][p] = rn;
        __syncthreads();
    }
    mats[(size_t)blockIdx.x * 1024 + tid] = rn;
}

// 8b. CRF tree level N
__global__ __launch_bounds__(1024) void crf_chainN_k(const float* __restrict__ min_,
                                                     float* __restrict__ mout,
                                                     int chunk) {
    const int tid = threadIdx.x;
    const int n = tid >> 5, p = tid & 31;
    __shared__ float Rl[2][NLBL][NLBL + 1];
    __shared__ float Al[2][NLBL][NLBL + 1];
    const size_t base = (size_t)blockIdx.x * chunk;
    float rn = min_[base * 1024 + tid];
    Rl[0][n][p] = rn;
    float anext = min_[(base + 1) * 1024 + tid];
    __syncthreads();
    for (int s = 1; s < chunk; ++s) {
        const int cur = (s - 1) & 1, nxt = s & 1;
        Al[nxt][n][p] = anext;
        if (s + 1 < chunk) anext = min_[(base + s + 1) * 1024 + tid];
        __syncthreads();
        float v[NLBL];
        #pragma unroll
        for (int k = 0; k < NLBL; ++k) v[k] = Al[nxt][n][k] + Rl[cur][k][p];
        float m = v[0];
        #pragma unroll
        for (int k = 1; k < NLBL; ++k) m = fmaxf(m, v[k]);
        float sum = 0.0f;
        #pragma unroll
        for (int k = 0; k < NLBL; ++k) sum += __expf(v[k] - m);
        rn = m + __logf(sum);
        Rl[nxt][n][p] = rn;
        __syncthreads();
    }
    mout[(size_t)blockIdx.x * 1024 + tid] = rn;
}

// 8c. CRF finish
__global__ __launch_bounds__(1024) void crf_finish_k(const float* __restrict__ min_,
                                                     const float* __restrict__ trans,
                                                     const float* __restrict__ gold,
                                                     float* __restrict__ out,
                                                     int chunk) {
    const int tid = threadIdx.x;
    const int n = tid >> 5, p = tid & 31;
    __shared__ float Rl[2][NLBL][NLBL + 1];
    __shared__ float Al[2][NLBL][NLBL + 1];
    __shared__ float af[NLBL];
    float rn = min_[tid];
    Rl[0][n][p] = rn;
    float anext = min_[1024 + tid];
    __syncthreads();
    for (int s = 1; s < chunk; ++s) {
        const int cur = (s - 1) & 1, nxt = s & 1;
        Al[nxt][n][p] = anext;
        if (s + 1 < chunk) anext = min_[(size_t)(s + 1) * 1024 + tid];
        __syncthreads();
        float v[NLBL];
        #pragma unroll
        for (int k = 0; k < NLBL; ++k) v[k] = Al[nxt][n][k] + Rl[cur][k][p];
        float m = v[0];
        #pragma unroll
        for (int k = 1; k < NLBL; ++k) m = fmaxf(m, v[k]);
        float sum = 0.0f;
        #pragma unroll
        for (int k = 0; k < NLBL; ++k) sum += __expf(v[k] - m);
        rn = m + __logf(sum);
        Rl[nxt][n][p] = rn;
        __syncthreads();
    }
    float val = rn + ((p == CLS_TAG) ? 0.0f : -10000.0f);
    float m = val;
    #pragma unroll
    for (int off = 16; off; off >>= 1) m = fmaxf(m, __shfl_xor(m, off, 32));
    float esum = __expf(val - m);
    #pragma unroll
    for (int off = 16; off; off >>= 1) esum += __shfl_xor(esum, off, 32);
    if (p == 0) af[n] = m + __logf(esum);
    __syncthreads();
    if (tid < NLBL) {
        float f = af[tid] + trans[SEP_TAG * NLBL + tid];
        float mm = f;
        #pragma unroll
        for (int off = 16; off; off >>= 1) mm = fmaxf(mm, __shfl_xor(mm, off, 32));
        float es = __expf(f - mm);
        #pragma unroll
        for (int off = 16; off; off >>= 1) es += __shfl_xor(es, off, 32);
        if (tid == 0) out[0] = mm + __logf(es) - gold[0];
    }
}

// ---------------- launch ----------------

extern "C" void kernel_launch(void* const* d_in, const int* in_sizes, int n_in,
                              void* d_out, int out_size, void* d_ws, size_t ws_size,
                              hipStream_t stream) {
    const int*   ids     = (const int*)d_in[0];
    const int*   target  = (const int*)d_in[2];
    const float* emb     = (const float*)d_in[3];
    const float* w_ih_f  = (const float*)d_in[4];
    const float* w_hh_f  = (const float*)d_in[5];
    const float* b_f     = (const float*)d_in[6];
    const float* w_ih_b  = (const float*)d_in[7];
    const float* w_hh_b  = (const float*)d_in[8];
    const float* b_b     = (const float*)d_in[9];
    const float* w_lin   = (const float*)d_in[10];
    const float* b_lin   = (const float*)d_in[11];
    const float* trans   = (const float*)d_in[12];
    const float* h0      = (const float*)d_in[13];
    const float* c0      = (const float*)d_in[14];
    float* out = (float*)d_out;

    char* ws = (char*)d_ws;
    size_t off = 0;
    float* xbuf   = (float*)(ws + off); off += (size_t)T_LEN * 256 * 4;       // 2 MB
    float* xprojP = (float*)(ws + off); off += (size_t)2 * T_LEN * G4 * 4;    // 16 MB
    float* hs     = (float*)(ws + off); off += (size_t)T_LEN * 512 * 4;       // 4 MB
    float* logits = (float*)(ws + off); off += (size_t)T_LEN * NLBL * 4;      // 256 KB
    float* srowP  = (float*)(ws + off); off += (size_t)2 * G4 * 4;            // 8 KB
    float* sh0v   = (float*)(ws + off); off += 16;
    float* gold   = (float*)(ws + off); off += 16;
    unsigned int* hq0 = (unsigned int*)(ws + off); off += (size_t)2 * 32 * 4;
    unsigned int* wq4 = (unsigned int*)(ws + off); off += (size_t)2 * G4 * 32 * 4; // 256 KB
    float* mats1 = xbuf;                 // alias xbuf (dead after gemm_xproj)
    float* mats2 = xbuf + 256 * 1024;

    gather_k<<<T_LEN, 256, 0, stream>>>(ids, emb, xbuf);
    quant_w_k<<<512, 256, 0, stream>>>(w_hh_f, w_hh_b, wq4, srowP);
    quant_h0_k<<<2, 64, 0, stream>>>(h0, hq0, sh0v);
    gemm_xproj_k<<<dim3(32, 32), 256, 0, stream>>>(xbuf, w_ih_f, w_ih_b, b_f, b_b, xprojP);
    lstm_rec_k<<<2, 512, 0, stream>>>(wq4, srowP, xprojP, hq0, sh0v, c0, hs);
    logits_k<<<dim3(256, 2), 128, 0, stream>>>(hs, w_lin, b_lin, logits);
    gold_k<<<1, 256, 0, stream>>>(trans, target, logits, gold);
    crf_chain0_k<<<256, 1024, 0, stream>>>(logits, trans, mats1);
    crf_chainN_k<<<16, 1024, 0, stream>>>(mats1, mats2, 16);
    crf_finish_k<<<1, 1024, 0, stream>>>(mats2, trans, gold, out, 16);
}

// Round 8
// 1612.688 us; speedup vs baseline: 1.3854x; 1.2209x over previous
//
#include <hip/hip_runtime.h>
#include <hip/hip_bf16.h>
#include <cstddef>

#define T_LEN 2048
#define H2 256
#define G4 1024   // 4*H2
#define NLBL 32
#define CLS_TAG 0
#define SEP_TAG 31

// ---------------- helpers ----------------

#if defined(__has_builtin)
#if __has_builtin(__builtin_amdgcn_sdot8)
#define HAS_SDOT8 1
#endif
#if __has_builtin(__builtin_amdgcn_rcpf)
#define HAS_RCPF 1
#endif
#endif

// int4x8 dot: acc += sum_m sext(a.nib[m]) * sext(b.nib[m])
__device__ __forceinline__ void dot8(int& acc, int a, int b) {
#if defined(HAS_SDOT8)
    acc = __builtin_amdgcn_sdot8(a, b, acc, false);
#elif defined(__gfx950__) || defined(__gfx942__) || defined(__gfx90a__)
    asm("v_dot8_i32_i4 %0, %1, %2, %0" : "+v"(acc) : "v"(a), "v"(b));
#else
    #pragma unroll
    for (int m = 0; m < 8; ++m) {
        int av = (a << (28 - 4 * m)) >> 28;
        int bv = (b << (28 - 4 * m)) >> 28;
        acc += av * bv;
    }
#endif
}

__device__ __forceinline__ float rcpf(float x) {
#ifdef HAS_RCPF
    return __builtin_amdgcn_rcpf(x);
#else
    return 1.0f / x;
#endif
}

__device__ __forceinline__ float sigf(float x) {
    return rcpf(1.0f + __expf(-x));
}

__device__ __forceinline__ float tanhf_(float x) {
    x = fminf(fmaxf(x, -15.0f), 15.0f);
    float e = __expf(2.0f * x);
    return (e - 1.0f) * rcpf(e + 1.0f);
}

// ---------------- kernels ----------------

// 1. gather embeddings
__global__ __launch_bounds__(256) void gather_k(const int* __restrict__ ids,
                                                const float* __restrict__ emb,
                                                float* __restrict__ xbuf) {
    int t = blockIdx.x;
    int row = ids[t];
    xbuf[(size_t)t * 256 + threadIdx.x] = emb[(size_t)row * 256 + threadIdx.x];
}

// 2. quantize w_hh to int4 (per-row symmetric, [-7,7]) into UNIT-MAJOR layout:
//    original row m (gate g = m>>8, unit u = m&255) -> wq4[((dir*256+u)*4+g)*32 + j],
//    dword j = elements 8j..8j+7, nibble m = element 8j+m. One wave per row.
__global__ __launch_bounds__(256) void quant_w_k(const float* __restrict__ w_hh_f,
                                                 const float* __restrict__ w_hh_b,
                                                 unsigned int* __restrict__ wq4,
                                                 float* __restrict__ srowP) {
    int wave = threadIdx.x >> 6, lane = threadIdx.x & 63;
    int rg = blockIdx.x * 4 + wave;              // 0..2047
    int dir = rg >> 10, m = rg & 1023;
    int g = m >> 8, u = m & 255;
    const float* src = (dir ? w_hh_b : w_hh_f) + (size_t)m * H2;
    float4 w4 = ((const float4*)src)[lane];      // elements 4*lane .. 4*lane+3
    float mx = fmaxf(fmaxf(fabsf(w4.x), fabsf(w4.y)), fmaxf(fabsf(w4.z), fabsf(w4.w)));
    #pragma unroll
    for (int off = 32; off; off >>= 1) mx = fmaxf(mx, __shfl_xor(mx, off, 64));
    float s = (mx > 0.0f) ? mx * (1.0f / 7.0f) : 1.0f;
    float inv = (mx > 0.0f) ? 7.0f * rcpf(mx) : 0.0f;
    int q0 = __float2int_rn(w4.x * inv);
    int q1 = __float2int_rn(w4.y * inv);
    int q2 = __float2int_rn(w4.z * inv);
    int q3 = __float2int_rn(w4.w * inv);
    unsigned int half = (unsigned)(q0 & 15) | ((unsigned)(q1 & 15) << 4) |
                        ((unsigned)(q2 & 15) << 8) | ((unsigned)(q3 & 15) << 12);
    unsigned int other = (unsigned int)__shfl_xor((int)half, 1, 64);
    if ((lane & 1) == 0)   // even lane: elems 8d..8d+3 (lo 16b), odd: 8d+4..8d+7
        wq4[(size_t)((dir * 256 + u) * 4 + g) * 32 + (lane >> 1)] = half | (other << 16);
    if (lane == 0) srowP[(dir * 256 + u) * 4 + g] = s;
}

// 3. quantize h0 to int4 (per-direction scale): dword j = units 8j..8j+7.
__global__ __launch_bounds__(64) void quant_h0_k(const float* __restrict__ h0,
                                                 unsigned int* __restrict__ hq0,
                                                 float* __restrict__ sh0) {
    int dir = blockIdx.x, lane = threadIdx.x;
    float4 h4 = ((const float4*)(h0 + (size_t)dir * H2))[lane];
    float mx = fmaxf(fmaxf(fabsf(h4.x), fabsf(h4.y)), fmaxf(fabsf(h4.z), fabsf(h4.w)));
    #pragma unroll
    for (int off = 32; off; off >>= 1) mx = fmaxf(mx, __shfl_xor(mx, off, 64));
    float s = (mx > 0.0f) ? mx * (1.0f / 7.0f) : 1.0f;
    float inv = (mx > 0.0f) ? 7.0f * rcpf(mx) : 0.0f;
    int q0 = __float2int_rn(h4.x * inv);
    int q1 = __float2int_rn(h4.y * inv);
    int q2 = __float2int_rn(h4.z * inv);
    int q3 = __float2int_rn(h4.w * inv);
    unsigned int half = (unsigned)(q0 & 15) | ((unsigned)(q1 & 15) << 4) |
                        ((unsigned)(q2 & 15) << 8) | ((unsigned)(q3 & 15) << 12);
    unsigned int other = (unsigned int)__shfl_xor((int)half, 1, 64);
    if ((lane & 1) == 0)
        hq0[dir * 32 + (lane >> 1)] = half | (other << 16);
    if (lane == 0) sh0[dir] = s;
}

// 4. xproj GEMM -> PERMUTED output: xprojP[dir][t][u*4+g]
__global__ __launch_bounds__(256) void gemm_xproj_k(const float* __restrict__ xbuf,
                                                    const float* __restrict__ w_ih_f,
                                                    const float* __restrict__ w_ih_b,
                                                    const float* __restrict__ b_f,
                                                    const float* __restrict__ b_b,
                                                    float* __restrict__ xprojP) {
    __shared__ float As[64][33];
    __shared__ float Bs[64][33];
    int tid = threadIdx.x;
    int t0 = blockIdx.x * 64;
    int n0 = blockIdx.y * 64;
    int tx = tid & 15, ty = tid >> 4;
    float acc[4][4] = {};
    for (int k0 = 0; k0 < 256; k0 += 32) {
        #pragma unroll
        for (int i = 0; i < 8; ++i) {
            int idx = tid + i * 256;
            int r = idx >> 5, kk = idx & 31;
            As[r][kk] = xbuf[(size_t)(t0 + r) * 256 + k0 + kk];
            int nn = n0 + r;
            const float* wsrc = (nn < 1024) ? (w_ih_f + (size_t)nn * 256)
                                            : (w_ih_b + (size_t)(nn - 1024) * 256);
            Bs[r][kk] = wsrc[k0 + kk];
        }
        __syncthreads();
        #pragma unroll
        for (int kk = 0; kk < 32; ++kk) {
            float a[4], b[4];
            #pragma unroll
            for (int i = 0; i < 4; ++i) a[i] = As[ty * 4 + i][kk];
            #pragma unroll
            for (int j = 0; j < 4; ++j) b[j] = Bs[tx * 4 + j][kk];
            #pragma unroll
            for (int i = 0; i < 4; ++i)
                #pragma unroll
                for (int j = 0; j < 4; ++j) acc[i][j] += a[i] * b[j];
        }
        __syncthreads();
    }
    #pragma unroll
    for (int j = 0; j < 4; ++j) {
        int nn = n0 + tx * 4 + j;
        int dir = nn >> 10, nl = nn & 1023;
        float bias = dir ? b_b[nl] : b_f[nl];
        int pidx = (nl & 255) * 4 + (nl >> 8);
        #pragma unroll
        for (int i = 0; i < 4; ++i) {
            int t = t0 + ty * 4 + i;
            xprojP[((size_t)dir * T_LEN + t) * G4 + pidx] = acc[i][j] + bias;
        }
    }
}

// 5. LSTM recurrence v8: 256 threads (4 waves, 1/SIMD), thread u owns ALL 4
//    int4 gate rows of unit u (128 dwords -> fits the 256-VGPR addressable
//    cap at launch_bounds(256,1): no forced AGPR split). No gate exchange;
//    h broadcast via 1 ds_read_b32 + readlane; one barrier over 4 waves;
//    depth-2 xproj prefetch (one dwordx4/thread/step).
__global__ __launch_bounds__(256, 1) void lstm_rec_k(const unsigned int* __restrict__ wq4,
                                                     const float* __restrict__ srowP,
                                                     const float* __restrict__ xprojP,
                                                     const unsigned int* __restrict__ hq0,
                                                     const float* __restrict__ sh0v,
                                                     const float* __restrict__ c0,
                                                     float* __restrict__ hs) {
    const int dir = blockIdx.x;
    const int u = threadIdx.x;            // unit 0..255
    const int lane = u & 63;
    __shared__ unsigned int hqs[2][32];   // 256 units x 4-bit, ping-pong

    // 4 gate rows x 32 int4-dwords
    int w0[32], w1[32], w2[32], w3[32];
    {
        const unsigned int* wr = wq4 + (size_t)(dir * 256 + u) * 128;
        #pragma unroll
        for (int j = 0; j < 32; ++j) w0[j] = (int)wr[j];
        #pragma unroll
        for (int j = 0; j < 32; ++j) w1[j] = (int)wr[32 + j];
        #pragma unroll
        for (int j = 0; j < 32; ++j) w2[j] = (int)wr[64 + j];
        #pragma unroll
        for (int j = 0; j < 32; ++j) w3[j] = (int)wr[96 + j];
    }
    float4 sr4 = ((const float4*)srowP)[dir * 256 + u];
    float sh = sh0v[dir];
    float c = c0[dir * H2 + u];
    const float4* xp4 = (const float4*)(xprojP + (size_t)dir * T_LEN * G4);
    if (u < 32) hqs[0][u] = hq0[dir * 32 + u];

    const int stp = dir ? -1 : 1;
    int ts0 = dir ? (T_LEN - 1) : 0;
    int ts1 = dir ? (T_LEN - 2) : 1;
    float4 zx = xp4[(size_t)ts0 * 256 + u];
    float4 zb = xp4[(size_t)ts1 * 256 + u];
    __syncthreads();

    for (int s = 0; s < T_LEN; ++s) {
        const int buf = s & 1;
        int ts = dir ? (T_LEN - 1 - s) : s;
        int tp = (s + 2 < T_LEN) ? (dir ? (T_LEN - 3 - s) : (s + 2)) : ts;
        float4 zc = xp4[(size_t)tp * 256 + u];            // prefetch s+2

        int hreg = (int)hqs[buf][lane & 31];              // dword (lane&31)
        int a0 = 0, a1 = 0, a2 = 0, a3 = 0;
        #pragma unroll
        for (int j = 0; j < 32; ++j) {
            int hj = __builtin_amdgcn_readlane(hreg, j);  // uniform broadcast
            dot8(a0, w0[j], hj);
            dot8(a1, w1[j], hj);
            dot8(a2, w2[j], hj);
            dot8(a3, w3[j], hj);
        }
        float zi = zx.x + sr4.x * sh * (float)a0;
        float zf = zx.y + sr4.y * sh * (float)a1;
        float zg = zx.z + sr4.z * sh * (float)a2;
        float zo = zx.w + sr4.w * sh * (float)a3;
        float ig = sigf(zi), fg = sigf(zf), gg = tanhf_(zg), og = sigf(zo);
        c = fg * c + ig * gg;
        float h = og * tanhf_(c);
        hs[(size_t)ts * 512 + dir * H2 + u] = h;
        int qv = __float2int_rn(fminf(fmaxf(h * 7.0f, -7.0f), 7.0f));
        int nib = qv & 15;
        int pn = __shfl_xor(nib, 1, 64);                  // neighbor unit's nibble
        if ((u & 1) == 0)                                 // byte u/2 = units u, u+1
            ((unsigned char*)&hqs[1 - buf][0])[u >> 1] =
                (unsigned char)((nib | (pn << 4)) & 255);
        sh = 1.0f / 7.0f;                                 // steady-state h scale
        zx = zb; zb = zc;
        __syncthreads();                                  // publish hqs[1-buf]
    }
}

// 6. logits
__global__ __launch_bounds__(128) void logits_k(const float* __restrict__ hs,
                                                const float* __restrict__ w_lin,
                                                const float* __restrict__ b_lin,
                                                float* __restrict__ logits) {
    __shared__ float wldT[512][17];
    __shared__ float hld[8][512];
    int tid = threadIdx.x;
    int t0 = blockIdx.x * 8;
    int n0 = blockIdx.y * 16;
    for (int i = tid; i < 16 * 512; i += 128) {
        int j = i >> 9, k = i & 511;
        wldT[k][j] = w_lin[(size_t)(n0 + j) * 512 + k];
    }
    for (int i = tid; i < 8 * 512; i += 128) {
        int tq = i >> 9, k = i & 511;
        hld[tq][k] = hs[(size_t)(t0 + tq) * 512 + k];
    }
    __syncthreads();
    int j = tid & 15, tq = tid >> 4;
    float acc = b_lin[n0 + j];
    #pragma unroll 8
    for (int k = 0; k < 512; ++k) acc += hld[tq][k] * wldT[k][j];
    logits[(size_t)(t0 + tq) * NLBL + n0 + j] = acc;
}

// 7. gold path score
__global__ __launch_bounds__(256) void gold_k(const float* __restrict__ trans,
                                              const int* __restrict__ target,
                                              const float* __restrict__ logits,
                                              float* __restrict__ gold) {
    __shared__ float red[256];
    int tid = threadIdx.x;
    float s = 0.0f;
    for (int t = tid; t < T_LEN; t += 256) {
        int cur = target[t];
        int prev = (t == 0) ? CLS_TAG : target[t - 1];
        s += trans[cur * NLBL + prev] + logits[(size_t)t * NLBL + cur];
    }
    if (tid == 0) s += trans[SEP_TAG * NLBL + target[T_LEN - 1]];
    red[tid] = s;
    __syncthreads();
    for (int st = 128; st; st >>= 1) {
        if (tid < st) red[tid] += red[tid + st];
        __syncthreads();
    }
    if (tid == 0) gold[0] = red[0];
}

// 8a. CRF tree level 0
__global__ __launch_bounds__(1024) void crf_chain0_k(const float* __restrict__ logits,
                                                     const float* __restrict__ trans,
                                                     float* __restrict__ mats) {
    const int tid = threadIdx.x;
    const int n = tid >> 5, p = tid & 31;
    __shared__ float Rl[2][NLBL][NLBL + 1];
    __shared__ float tl[NLBL][NLBL + 1];
    const int t0 = blockIdx.x * 8;
    float e[8];
    #pragma unroll
    for (int s = 0; s < 8; ++s) e[s] = logits[(size_t)(t0 + s) * NLBL + n];
    float myt = trans[n * NLBL + p];
    tl[n][p] = myt;
    __syncthreads();
    float tr[NLBL];
    #pragma unroll
    for (int k = 0; k < NLBL; ++k) tr[k] = tl[n][k];
    Rl[0][n][p] = myt + e[0];
    __syncthreads();
    float rn = 0.0f;
    for (int s = 1; s < 8; ++s) {
        const int cur = (s - 1) & 1, nxt = s & 1;
        float v[NLBL];
        #pragma unroll
        for (int k = 0; k < NLBL; ++k) v[k] = tr[k] + Rl[cur][k][p];
        float m = v[0];
        #pragma unroll
        for (int k = 1; k < NLBL; ++k) m = fmaxf(m, v[k]);
        float sum = 0.0f;
        #pragma unroll
        for (int k = 0; k < NLBL; ++k) sum += __expf(v[k] - m);
        rn = e[s] + m + __logf(sum);
        Rl[nxt][n][p] = rn;
        __syncthreads();
    }
    mats[(size_t)blockIdx.x * 1024 + tid] = rn;
}

// 8b. CRF tree level N
__global__ __launch_bounds__(1024) void crf_chainN_k(const float* __restrict__ min_,
                                                     float* __restrict__ mout,
                                                     int chunk) {
    const int tid = threadIdx.x;
    const int n = tid >> 5, p = tid & 31;
    __shared__ float Rl[2][NLBL][NLBL + 1];
    __shared__ float Al[2][NLBL][NLBL + 1];
    const size_t base = (size_t)blockIdx.x * chunk;
    float rn = min_[base * 1024 + tid];
    Rl[0][n][p] = rn;
    float anext = min_[(base + 1) * 1024 + tid];
    __syncthreads();
    for (int s = 1; s < chunk; ++s) {
        const int cur = (s - 1) & 1, nxt = s & 1;
        Al[nxt][n][p] = anext;
        if (s + 1 < chunk) anext = min_[(base + s + 1) * 1024 + tid];
        __syncthreads();
        float v[NLBL];
        #pragma unroll
        for (int k = 0; k < NLBL; ++k) v[k] = Al[nxt][n][k] + Rl[cur][k][p];
        float m = v[0];
        #pragma unroll
        for (int k = 1; k < NLBL; ++k) m = fmaxf(m, v[k]);
        float sum = 0.0f;
        #pragma unroll
        for (int k = 0; k < NLBL; ++k) sum += __expf(v[k] - m);
        rn = m + __logf(sum);
        Rl[nxt][n][p] = rn;
        __syncthreads();
    }
    mout[(size_t)blockIdx.x * 1024 + tid] = rn;
}

// 8c. CRF finish
__global__ __launch_bounds__(1024) void crf_finish_k(const float* __restrict__ min_,
                                                     const float* __restrict__ trans,
                                                     const float* __restrict__ gold,
                                                     float* __restrict__ out,
                                                     int chunk) {
    const int tid = threadIdx.x;
    const int n = tid >> 5, p = tid & 31;
    __shared__ float Rl[2][NLBL][NLBL + 1];
    __shared__ float Al[2][NLBL][NLBL + 1];
    __shared__ float af[NLBL];
    float rn = min_[tid];
    Rl[0][n][p] = rn;
    float anext = min_[1024 + tid];
    __syncthreads();
    for (int s = 1; s < chunk; ++s) {
        const int cur = (s - 1) & 1, nxt = s & 1;
        Al[nxt][n][p] = anext;
        if (s + 1 < chunk) anext = min_[(size_t)(s + 1) * 1024 + tid];
        __syncthreads();
        float v[NLBL];
        #pragma unroll
        for (int k = 0; k < NLBL; ++k) v[k] = Al[nxt][n][k] + Rl[cur][k][p];
        float m = v[0];
        #pragma unroll
        for (int k = 1; k < NLBL; ++k) m = fmaxf(m, v[k]);
        float sum = 0.0f;
        #pragma unroll
        for (int k = 0; k < NLBL; ++k) sum += __expf(v[k] - m);
        rn = m + __logf(sum);
        Rl[nxt][n][p] = rn;
        __syncthreads();
    }
    float val = rn + ((p == CLS_TAG) ? 0.0f : -10000.0f);
    float m = val;
    #pragma unroll
    for (int off = 16; off; off >>= 1) m = fmaxf(m, __shfl_xor(m, off, 32));
    float esum = __expf(val - m);
    #pragma unroll
    for (int off = 16; off; off >>= 1) esum += __shfl_xor(esum, off, 32);
    if (p == 0) af[n] = m + __logf(esum);
    __syncthreads();
    if (tid < NLBL) {
        float f = af[tid] + trans[SEP_TAG * NLBL + tid];
        float mm = f;
        #pragma unroll
        for (int off = 16; off; off >>= 1) mm = fmaxf(mm, __shfl_xor(mm, off, 32));
        float es = __expf(f - mm);
        #pragma unroll
        for (int off = 16; off; off >>= 1) es += __shfl_xor(es, off, 32);
        if (tid == 0) out[0] = mm + __logf(es) - gold[0];
    }
}

// ---------------- launch ----------------

extern "C" void kernel_launch(void* const* d_in, const int* in_sizes, int n_in,
                              void* d_out, int out_size, void* d_ws, size_t ws_size,
                              hipStream_t stream) {
    const int*   ids     = (const int*)d_in[0];
    const int*   target  = (const int*)d_in[2];
    const float* emb     = (const float*)d_in[3];
    const float* w_ih_f  = (const float*)d_in[4];
    const float* w_hh_f  = (const float*)d_in[5];
    const float* b_f     = (const float*)d_in[6];
    const float* w_ih_b  = (const float*)d_in[7];
    const float* w_hh_b  = (const float*)d_in[8];
    const float* b_b     = (const float*)d_in[9];
    const float* w_lin   = (const float*)d_in[10];
    const float* b_lin   = (const float*)d_in[11];
    const float* trans   = (const float*)d_in[12];
    const float* h0      = (const float*)d_in[13];
    const float* c0      = (const float*)d_in[14];
    float* out = (float*)d_out;

    char* ws = (char*)d_ws;
    size_t off = 0;
    float* xbuf   = (float*)(ws + off); off += (size_t)T_LEN * 256 * 4;       // 2 MB
    float* xprojP = (float*)(ws + off); off += (size_t)2 * T_LEN * G4 * 4;    // 16 MB
    float* hs     = (float*)(ws + off); off += (size_t)T_LEN * 512 * 4;       // 4 MB
    float* logits = (float*)(ws + off); off += (size_t)T_LEN * NLBL * 4;      // 256 KB
    float* srowP  = (float*)(ws + off); off += (size_t)2 * G4 * 4;            // 8 KB
    float* sh0v   = (float*)(ws + off); off += 16;
    float* gold   = (float*)(ws + off); off += 16;
    unsigned int* hq0 = (unsigned int*)(ws + off); off += (size_t)2 * 32 * 4;
    unsigned int* wq4 = (unsigned int*)(ws + off); off += (size_t)2 * G4 * 32 * 4; // 256 KB
    float* mats1 = xbuf;                 // alias xbuf (dead after gemm_xproj)
    float* mats2 = xbuf + 256 * 1024;

    gather_k<<<T_LEN, 256, 0, stream>>>(ids, emb, xbuf);
    quant_w_k<<<512, 256, 0, stream>>>(w_hh_f, w_hh_b, wq4, srowP);
    quant_h0_k<<<2, 64, 0, stream>>>(h0, hq0, sh0v);
    gemm_xproj_k<<<dim3(32, 32), 256, 0, stream>>>(xbuf, w_ih_f, w_ih_b, b_f, b_b, xprojP);
    lstm_rec_k<<<2, 256, 0, stream>>>(wq4, srowP, xprojP, hq0, sh0v, c0, hs);
    logits_k<<<dim3(256, 2), 128, 0, stream>>>(hs, w_lin, b_lin, logits);
    gold_k<<<1, 256, 0, stream>>>(trans, target, logits, gold);
    crf_chain0_k<<<256, 1024, 0, stream>>>(logits, trans, mats1);
    crf_chainN_k<<<16, 1024, 0, stream>>>(mats1, mats2, 16);
    crf_finish_k<<<1, 1024, 0, stream>>>(mats2, trans, gold, out, 16);
}